// Round 1
// baseline (295.133 us; speedup 1.0000x reference)
//
#include <hip/hip_runtime.h>

// MS-G3D block. bf16-MFMA, t-chunk=2 fused k1 with fragment-swizzled weights.
// This rev: software-pipelined weight prefetch in k1 (wa/bfr rotated one ps
// ahead; loads covered by ~30 MFMAs); k3 t-chunk=1 with [n][t][o][u] HR layout
// for fully-coalesced b128 loads.
// N=8, C=96, T=128, V=25, WIN=3, VL=75, NS=6.

#define NB 8
#define CB 96
#define TB 128
#define VB 25
#define VLB 75
#define EPSB 1e-5f
#define XRS 104   // xraw row stride (shorts)
#define TMS 104   // tmp row stride
#define HBS 296   // hnb row stride (shorts)

typedef __attribute__((ext_vector_type(8))) short bf16x8;
typedef __attribute__((ext_vector_type(4))) float f32x4;

__device__ inline unsigned short f2bf(float f) {
  unsigned int u = __float_as_uint(f);
  u = (u + 0x7FFFu + ((u >> 16) & 1u)) >> 16;
  return (unsigned short)u;
}
__device__ inline float bf2f(unsigned short u) {
  return __uint_as_float(((unsigned int)u) << 16);
}

// ---------------- K0: build fragment-swizzled bf16 weights; zero stats -------
// Wsw  [ps][wave][kk][lane][j] : W_ps[o=wave*16+(lane&15)][c=kk*32+(lane>>4)*8+j]
// ABsw [ps][nt][kk][lane][j]   : AB_ps[u=nt*16+(lane&15)][u'=kk*32+(lane>>4)*8+j]
// Wosw [wave][kk][lane][j]     : Wo[o=wave*16+(lane&15)][k=kk*32+(lane>>4)*8+j]
__global__ __launch_bounds__(256) void k0_init(
    const float* __restrict__ As, const float* __restrict__ Bs,
    const float* __restrict__ Ar, const float* __restrict__ Wm,
    const float* __restrict__ Wo,
    unsigned short* __restrict__ ABsw, unsigned short* __restrict__ Wsw,
    unsigned short* __restrict__ Wosw, float* __restrict__ stats) {
  int i = blockIdx.x * 256 + threadIdx.x;
  if (i < 110592) {                     // Wsw: 12*6*3*512
    int ps = i / 9216, r = i % 9216;
    int wv = r / 1536, r2 = r % 1536;
    int kk = r2 / 512, r3 = r2 % 512;
    int lane = r3 / 8, j = r3 % 8;
    int o = wv * 16 + (lane & 15);
    int c = kk * 32 + (lane >> 4) * 8 + j;
    Wsw[i] = f2bf(Wm[o * 1152 + ps * 96 + c]);
  }
  if (i < 92160) {                      // ABsw: 12*5*3*512
    int ps = i / 7680, r = i % 7680;
    int nt = r / 1536, r2 = r % 1536;
    int kk = r2 / 512, r3 = r2 % 512;
    int lane = r3 / 8, j = r3 % 8;
    int u = nt * 16 + (lane & 15);
    int up = kk * 32 + (lane >> 4) * 8 + j;
    float v = 0.f;
    if (u < 75 && up < 75) {
      int path = ps / 6, s = ps % 6;
      int idx = (s * 75 + u) * 75 + up;
      v = (path == 0 ? As[idx] : Bs[idx]) + Ar[idx];
    }
    ABsw[i] = f2bf(v);
  }
  if (i < 27648) {                      // Wosw: 6*9*512
    int wv = i / 4608, r = i % 4608;
    int kk = r / 512, r3 = r % 512;
    int lane = r3 / 8, j = r3 % 8;
    int o = wv * 16 + (lane & 15);
    int k = kk * 32 + (lane >> 4) * 8 + j;
    Wosw[i] = f2bf(Wo[o * 288 + k]);
  }
  if (i < 384) stats[i] = 0.f;
}

// ---------------- K1: t2 fused (MLP -> agg) x12 MFMA, pipelined weights -----
// grid = N*T/2 = 512 blocks, 384 threads (6 waves). Wave w owns o-rows [16w,16w+16).
// Steady state per ps: [load wa(ps+1)] G2(ps) [load bfr(ps+1)] G1(ps+1).
// Each weight load is covered by ~30 MFMAs of independent work (ILP latency
// hiding at fixed 12 waves/CU; VGPR cap 170 via __launch_bounds__(384,3)).
__global__ __launch_bounds__(384, 3) void k1t2(
    const float* __restrict__ x, const unsigned short* __restrict__ ABsw,
    const unsigned short* __restrict__ Wsw, const float* __restrict__ bm,
    unsigned short* __restrict__ h_relu, float* __restrict__ stats1) {
  __shared__ unsigned short xraw[112 * XRS];     // rows r=tt_rel*25+v, 100..111 zero
  __shared__ unsigned short tmp_s[2][96 * TMS];  // per-dt tmp [o][u']
  __shared__ float st1s[96], st2s[96];
  const int tid = threadIdx.x;
  const int n = blockIdx.x >> 6, t0 = (blockIdx.x & 63) * 2;
  const int wave = tid >> 6, lane = tid & 63;
  const int l15 = lane & 15, quad = lane >> 4, q8 = quad * 8;
  const int wrow16 = wave * 16;

  // stage raw x slice: tt = t0-1 .. t0+2 (100 rows), zero-pad rows to 112
  for (int idx = tid; idx < 96 * 112; idx += 384) {
    int c = idx / 112, r = idx - c * 112;
    float v = 0.f;
    if (r < 100) {
      int tt = t0 - 1 + r / 25, vv = r % 25;
      if (tt >= 0 && tt < TB) v = x[((n * CB + c) * TB + tt) * VB + vv];
    }
    xraw[r * XRS + c] = f2bf(v);
  }
  // zero tmp K-pad cols [80,96) for both buffers (cols 75..79 may hold finite
  // garbage each ps; ABsw rows u'>=75 are zeroed in k0 so they contribute 0)
  for (int idx = tid; idx < 2 * 96 * 16; idx += 384) {
    int b = idx / (96 * 16), rem = idx - b * 96 * 16;
    tmp_s[b][(rem / 16) * TMS + 80 + rem % 16] = 0;
  }
  __syncthreads();

  const f32x4 zf = {0.f, 0.f, 0.f, 0.f};
  f32x4 acc2[2][5];
#pragma unroll
  for (int d = 0; d < 2; ++d)
#pragma unroll
    for (int nt = 0; nt < 5; ++nt) acc2[d][nt] = zf;

  const unsigned short* Wbase = Wsw + wave * 1536 + lane * 8;   // + ps*9216 + kk*512
  const unsigned short* Bbase = ABsw + lane * 8;                // + ps*7680 + (nt*3+kk)*512

  bf16x8 wa[3], bfr[15];

  // GEMM1 for both dt using current wa; writes tmp_s[0]/tmp_s[1] (wave-private rows)
  auto g1both = [&]() {
    f32x4 acc1[5];
#pragma unroll
    for (int nt = 0; nt < 5; ++nt) acc1[nt] = zf;
#pragma unroll
    for (int kk = 0; kk < 3; ++kk)
#pragma unroll
      for (int nt = 0; nt < 5; ++nt) {
        bf16x8 b = *reinterpret_cast<const bf16x8*>(&xraw[(nt * 16 + l15) * XRS + kk * 32 + q8]);
        acc1[nt] = __builtin_amdgcn_mfma_f32_16x16x32_bf16(wa[kk], b, acc1[nt], 0, 0, 0);
      }
#pragma unroll
    for (int nt = 0; nt < 5; ++nt) {
      int col = nt * 16 + l15;
#pragma unroll
      for (int r = 0; r < 4; ++r)
        tmp_s[0][(wrow16 + quad * 4 + r) * TMS + col] = f2bf(acc1[nt][r]);
    }
    // dt=1 (covers tmp0 write->read latency)
#pragma unroll
    for (int nt = 0; nt < 5; ++nt) acc1[nt] = zf;
#pragma unroll
    for (int kk = 0; kk < 3; ++kk)
#pragma unroll
      for (int nt = 0; nt < 5; ++nt) {
        bf16x8 b = *reinterpret_cast<const bf16x8*>(&xraw[(25 + nt * 16 + l15) * XRS + kk * 32 + q8]);
        acc1[nt] = __builtin_amdgcn_mfma_f32_16x16x32_bf16(wa[kk], b, acc1[nt], 0, 0, 0);
      }
#pragma unroll
    for (int nt = 0; nt < 5; ++nt) {
      int col = nt * 16 + l15;
#pragma unroll
      for (int r = 0; r < 4; ++r)
        tmp_s[1][(wrow16 + quad * 4 + r) * TMS + col] = f2bf(acc1[nt][r]);
    }
  };

  // prologue: weights(ps=0) + G1(0)
#pragma unroll
  for (int kk = 0; kk < 3; ++kk)
    wa[kk] = *reinterpret_cast<const bf16x8*>(Wbase + kk * 512);
#pragma unroll
  for (int i = 0; i < 15; ++i)
    bfr[i] = *reinterpret_cast<const bf16x8*>(Bbase + i * 512);
  g1both();

#pragma unroll
  for (int ps = 0; ps < 12; ++ps) {
    // issue wa(ps+1) — consumed by G1(ps+1) after G2's 30 MFMAs
    if (ps < 11) {
#pragma unroll
      for (int kk = 0; kk < 3; ++kk)
        wa[kk] = *reinterpret_cast<const bf16x8*>(Wbase + (ps + 1) * 9216 + kk * 512);
    }
    // GEMM2 both dt using bfr(ps) (issued one ps ago); reads tmp written by G1(ps)
#pragma unroll
    for (int kk = 0; kk < 3; ++kk) {
      bf16x8 a0 = *reinterpret_cast<const bf16x8*>(&tmp_s[0][(wrow16 + l15) * TMS + kk * 32 + q8]);
#pragma unroll
      for (int nt = 0; nt < 5; ++nt)
        acc2[0][nt] = __builtin_amdgcn_mfma_f32_16x16x32_bf16(a0, bfr[nt * 3 + kk], acc2[0][nt], 0, 0, 0);
      bf16x8 a1 = *reinterpret_cast<const bf16x8*>(&tmp_s[1][(wrow16 + l15) * TMS + kk * 32 + q8]);
#pragma unroll
      for (int nt = 0; nt < 5; ++nt)
        acc2[1][nt] = __builtin_amdgcn_mfma_f32_16x16x32_bf16(a1, bfr[nt * 3 + kk], acc2[1][nt], 0, 0, 0);
    }
    if (ps < 11) {
      // issue bfr(ps+1) — consumed by G2(ps+1) after G1's 30 MFMAs
#pragma unroll
      for (int i = 0; i < 15; ++i)
        bfr[i] = *reinterpret_cast<const bf16x8*>(Bbase + (ps + 1) * 7680 + i * 512);
      // G1(ps+1): overwrites tmp AFTER G2's reads (same-wave DS ordering)
      g1both();
    }
  }

  // epilogue: bias + relu + bf16 store (HR layout [n][t][o][u]) + BN1 stats
  const int orow = wrow16 + quad * 4;
  float s1[4] = {0.f, 0.f, 0.f, 0.f}, s2[4] = {0.f, 0.f, 0.f, 0.f};
#pragma unroll
  for (int d = 0; d < 2; ++d) {
    const int t = t0 + d;
#pragma unroll
    for (int r = 0; r < 4; ++r) {
      const int o = orow + r;
      const float bias = bm[o];
      unsigned short* hp = h_relu + ((n * TB + t) * CB + o) * VLB;
#pragma unroll
      for (int nt = 0; nt < 5; ++nt) {
        int u = nt * 16 + l15;
        if (u < VLB) {
          float v = acc2[d][nt][r] + bias;
          v = v > 0.f ? v : 0.f;
          hp[u] = f2bf(v);
          s1[r] += v;
          s2[r] += v * v;
        }
      }
    }
  }
#pragma unroll
  for (int off = 1; off < 16; off <<= 1) {
#pragma unroll
    for (int r = 0; r < 4; ++r) {
      s1[r] += __shfl_xor(s1[r], off, 64);
      s2[r] += __shfl_xor(s2[r], off, 64);
    }
  }
  if (l15 == 0) {
#pragma unroll
    for (int r = 0; r < 4; ++r) { st1s[orow + r] = s1[r]; st2s[orow + r] = s2[r]; }
  }
  __syncthreads();
  if (tid < 96) {
    atomicAdd(&stats1[tid], st1s[tid]);
    atomicAdd(&stats1[96 + tid], st2s[tid]);
  }
}

// ---------------- K3: BN1-finalize + relu + out_conv (MFMA, 1 t/blk) --------
// grid = N*T = 1024 blocks. HR is [n][t][o][u]: the block's whole input slice
// is 7200 contiguous bf16 -> 900 coalesced b128 loads. LDS 20.5KB -> 4 blk/CU.
__global__ __launch_bounds__(384, 4) void k3n(
    const unsigned short* __restrict__ h_relu, const float* __restrict__ stats1,
    const float* __restrict__ g1, const float* __restrict__ bt1,
    const unsigned short* __restrict__ Wosw, const float* __restrict__ bo,
    float* __restrict__ out_pre, float* __restrict__ stats2) {
  __shared__ unsigned short hnb[32 * HBS];
  __shared__ float a1s[96], b1s[96];
  __shared__ float st1[96], st2[96];
  const int tid = threadIdx.x;
  const int n = blockIdx.x >> 7, t = blockIdx.x & 127;

  if (tid < 96) {
    const float inv = 1.f / (8.f * 128.f * 75.f);
    float m = stats1[tid] * inv;
    float var = stats1[96 + tid] * inv - m * m;
    float a = g1[tid] * rsqrtf(var + EPSB);
    a1s[tid] = a;
    b1s[tid] = bt1[tid] - m * a;
  }
  for (int idx = tid; idx < 7 * HBS; idx += 384) hnb[25 * HBS + idx] = 0;
  __syncthreads();

  const unsigned short* hp = h_relu + (n * TB + t) * (CB * VLB);
  for (int i8 = tid; i8 < 900; i8 += 384) {
    bf16x8 v = *reinterpret_cast<const bf16x8*>(hp + i8 * 8);
    const int e = i8 * 8;
#pragma unroll
    for (int j = 0; j < 8; ++j) {
      int ee = e + j;
      int i = ee / 75, u = ee - i * 75;
      float val = a1s[i] * bf2f((unsigned short)v[j]) + b1s[i];
      val = val > 0.f ? val : 0.f;
      int w = u / 25, vv = u - w * 25;
      hnb[vv * HBS + i * 3 + w] = f2bf(val);
    }
  }
  __syncthreads();

  const int wave = tid >> 6, lane = tid & 63;
  const int l15 = lane & 15, quad = lane >> 4, q8 = quad * 8;
  const f32x4 zf = {0.f, 0.f, 0.f, 0.f};
  f32x4 acc[2] = {zf, zf};
  const unsigned short* Apw = Wosw + wave * 4608 + lane * 8;
#pragma unroll
  for (int kk = 0; kk < 9; ++kk) {
    bf16x8 a = *reinterpret_cast<const bf16x8*>(Apw + kk * 512);
    bf16x8 b0 = *reinterpret_cast<const bf16x8*>(&hnb[l15 * HBS + kk * 32 + q8]);
    bf16x8 b1 = *reinterpret_cast<const bf16x8*>(&hnb[(16 + l15) * HBS + kk * 32 + q8]);
    acc[0] = __builtin_amdgcn_mfma_f32_16x16x32_bf16(a, b0, acc[0], 0, 0, 0);
    acc[1] = __builtin_amdgcn_mfma_f32_16x16x32_bf16(a, b1, acc[1], 0, 0, 0);
  }

  const int orow = wave * 16 + quad * 4;
  float s1[4] = {0.f, 0.f, 0.f, 0.f}, s2[4] = {0.f, 0.f, 0.f, 0.f};
#pragma unroll
  for (int nt = 0; nt < 2; ++nt) {
    int v = nt * 16 + l15;
    if (v < VB) {
#pragma unroll
      for (int r = 0; r < 4; ++r) {
        const int o = orow + r;
        float val = acc[nt][r] + bo[o];
        out_pre[((n * CB + o) * TB + t) * VB + v] = val;
        s1[r] += val;
        s2[r] += val * val;
      }
    }
  }
#pragma unroll
  for (int off = 1; off < 16; off <<= 1) {
#pragma unroll
    for (int r = 0; r < 4; ++r) {
      s1[r] += __shfl_xor(s1[r], off, 64);
      s2[r] += __shfl_xor(s2[r], off, 64);
    }
  }
  if (l15 == 0) {
#pragma unroll
    for (int r = 0; r < 4; ++r) { st1[orow + r] = s1[r]; st2[orow + r] = s2[r]; }
  }
  __syncthreads();
  if (tid < 96) {
    atomicAdd(&stats2[tid], st1[tid]);
    atomicAdd(&stats2[96 + tid], st2[tid]);
  }
}

// ---------------- K5: BN2 finalize (float4 elementwise) ----------------
__global__ __launch_bounds__(256) void k5_bn2(
    const float* __restrict__ out_pre, const float* __restrict__ stats2,
    const float* __restrict__ g2, const float* __restrict__ bt2,
    float* __restrict__ out) {
  int idx = blockIdx.x * 256 + threadIdx.x;
  if (idx >= NB * CB * TB * VB / 4) return;
  int o = (idx / (TB * VB / 4)) % CB;
  const float inv = 1.f / (8.f * 128.f * 25.f);
  float m = stats2[o] * inv;
  float var = stats2[96 + o] * inv - m * m;
  float a = g2[o] * rsqrtf(var + EPSB);
  float b = bt2[o] - m * a;
  f32x4 vin = reinterpret_cast<const f32x4*>(out_pre)[idx];
  f32x4 vo;
#pragma unroll
  for (int j = 0; j < 4; ++j) vo[j] = a * vin[j] + b;
  reinterpret_cast<f32x4*>(out)[idx] = vo;
}

extern "C" void kernel_launch(void* const* d_in, const int* in_sizes, int n_in,
                              void* d_out, int out_size, void* d_ws, size_t ws_size,
                              hipStream_t stream) {
  const float* x   = (const float*)d_in[0];
  const float* As  = (const float*)d_in[1];
  const float* Bs  = (const float*)d_in[2];
  const float* Ar  = (const float*)d_in[3];
  const float* Wm  = (const float*)d_in[4];
  const float* bm  = (const float*)d_in[5];
  const float* g1  = (const float*)d_in[6];
  const float* bt1 = (const float*)d_in[7];
  const float* Wo  = (const float*)d_in[8];
  const float* bo  = (const float*)d_in[9];
  const float* g2  = (const float*)d_in[10];
  const float* bt2 = (const float*)d_in[11];
  float* out = (float*)d_out;

  char* base = (char*)d_ws;
  unsigned short* HR   = (unsigned short*)base;                  // 14,745,600 B
  float* out_pre       = (float*)(base + 14745600);              //  9,830,400 B
  unsigned short* ABsw = (unsigned short*)(base + 24576000);     //    184,320 B
  unsigned short* Wsw  = (unsigned short*)(base + 24760320);     //    221,184 B
  unsigned short* Wosw = (unsigned short*)(base + 24981504);     //     55,296 B
  float* stats         = (float*)(base + 25036800);              //      1,536 B
  float* stats1 = stats, *stats2 = stats + 192;

  k0_init<<<432, 256, 0, stream>>>(As, Bs, Ar, Wm, Wo, ABsw, Wsw, Wosw, stats);
  k1t2<<<NB * TB / 2, 384, 0, stream>>>(x, ABsw, Wsw, bm, HR, stats1);
  k3n<<<NB * TB, 384, 0, stream>>>(HR, stats1, g1, bt1, Wosw, bo, out_pre, stats2);
  k5_bn2<<<(NB * CB * TB * VB / 4 + 255) / 256, 256, 0, stream>>>(out_pre, stats2, g2, bt2, out);
}

// Round 2
// 294.816 us; speedup vs baseline: 1.0011x; 1.0011x over previous
//
#include <hip/hip_runtime.h>

// MS-G3D block. bf16-MFMA, t-chunk=2 fused k1 with fragment-swizzled weights.
// This rev: rotated software pipeline in k1 WITHOUT lambdas (round-1's lambda
// captured wa[] by reference -> address taken -> fragment arrays spilled to
// scratch: FETCH 14.6->241MB). G1 is a __forceinline__ fn taking W-fragments
// BY VALUE. Steady state per ps: [load wa(ps+1)] G2(ps) [load bf(ps+1)] G1(ps+1)
// so every global load is covered by ~30 MFMAs. launch_bounds(384,3): LDS
// limits to 2 blocks/CU anyway; cap VGPR at 170 so bf[15]+acc2 stay live.
// k3: t-chunk=1 with [n][t][o][u] HR layout for fully-coalesced b128 loads.
// N=8, C=96, T=128, V=25, WIN=3, VL=75, NS=6.

#define NB 8
#define CB 96
#define TB 128
#define VB 25
#define VLB 75
#define EPSB 1e-5f
#define XRS 104   // xraw row stride (shorts)
#define TMS 104   // tmp row stride
#define HBS 296   // hnb row stride (shorts)

typedef __attribute__((ext_vector_type(8))) short bf16x8;
typedef __attribute__((ext_vector_type(4))) float f32x4;

__device__ inline unsigned short f2bf(float f) {
  unsigned int u = __float_as_uint(f);
  u = (u + 0x7FFFu + ((u >> 16) & 1u)) >> 16;
  return (unsigned short)u;
}
__device__ inline float bf2f(unsigned short u) {
  return __uint_as_float(((unsigned int)u) << 16);
}

// ---------------- K0: build fragment-swizzled bf16 weights; zero stats -------
// Wsw  [ps][wave][kk][lane][j] : W_ps[o=wave*16+(lane&15)][c=kk*32+(lane>>4)*8+j]
// ABsw [ps][nt][kk][lane][j]   : AB_ps[u=nt*16+(lane&15)][u'=kk*32+(lane>>4)*8+j]
// Wosw [wave][kk][lane][j]     : Wo[o=wave*16+(lane&15)][k=kk*32+(lane>>4)*8+j]
__global__ __launch_bounds__(256) void k0_init(
    const float* __restrict__ As, const float* __restrict__ Bs,
    const float* __restrict__ Ar, const float* __restrict__ Wm,
    const float* __restrict__ Wo,
    unsigned short* __restrict__ ABsw, unsigned short* __restrict__ Wsw,
    unsigned short* __restrict__ Wosw, float* __restrict__ stats) {
  int i = blockIdx.x * 256 + threadIdx.x;
  if (i < 110592) {                     // Wsw: 12*6*3*512
    int ps = i / 9216, r = i % 9216;
    int wv = r / 1536, r2 = r % 1536;
    int kk = r2 / 512, r3 = r2 % 512;
    int lane = r3 / 8, j = r3 % 8;
    int o = wv * 16 + (lane & 15);
    int c = kk * 32 + (lane >> 4) * 8 + j;
    Wsw[i] = f2bf(Wm[o * 1152 + ps * 96 + c]);
  }
  if (i < 92160) {                      // ABsw: 12*5*3*512
    int ps = i / 7680, r = i % 7680;
    int nt = r / 1536, r2 = r % 1536;
    int kk = r2 / 512, r3 = r2 % 512;
    int lane = r3 / 8, j = r3 % 8;
    int u = nt * 16 + (lane & 15);
    int up = kk * 32 + (lane >> 4) * 8 + j;
    float v = 0.f;
    if (u < 75 && up < 75) {
      int path = ps / 6, s = ps % 6;
      int idx = (s * 75 + u) * 75 + up;
      v = (path == 0 ? As[idx] : Bs[idx]) + Ar[idx];
    }
    ABsw[i] = f2bf(v);
  }
  if (i < 27648) {                      // Wosw: 6*9*512
    int wv = i / 4608, r = i % 4608;
    int kk = r / 512, r3 = r % 512;
    int lane = r3 / 8, j = r3 % 8;
    int o = wv * 16 + (lane & 15);
    int k = kk * 32 + (lane >> 4) * 8 + j;
    Wosw[i] = f2bf(Wo[o * 288 + k]);
  }
  if (i < 384) stats[i] = 0.f;
}

// GEMM1 for both dt: W-fragments passed BY VALUE (no address taken -> regs).
// Writes the wave's private 16-row stripe of tmp0/tmp1. tmp cols 75..79 get
// garbage-but-finite values; ABsw rows u'>=75 are zeroed in k0 so they
// contribute 0 to GEMM2.
__device__ __forceinline__ void g1both_fn(
    const unsigned short* xraw, unsigned short* tmp0, unsigned short* tmp1,
    bf16x8 w0, bf16x8 w1, bf16x8 w2, int l15, int q8, int row4) {
  const f32x4 zf = {0.f, 0.f, 0.f, 0.f};
  bf16x8 w[3] = {w0, w1, w2};
  f32x4 acc1[5];
#pragma unroll
  for (int nt = 0; nt < 5; ++nt) acc1[nt] = zf;
#pragma unroll
  for (int kk = 0; kk < 3; ++kk)
#pragma unroll
    for (int nt = 0; nt < 5; ++nt) {
      bf16x8 b = *reinterpret_cast<const bf16x8*>(&xraw[(nt * 16 + l15) * XRS + kk * 32 + q8]);
      acc1[nt] = __builtin_amdgcn_mfma_f32_16x16x32_bf16(w[kk], b, acc1[nt], 0, 0, 0);
    }
#pragma unroll
  for (int nt = 0; nt < 5; ++nt) {
    int col = nt * 16 + l15;
#pragma unroll
    for (int r = 0; r < 4; ++r)
      tmp0[(row4 + r) * TMS + col] = f2bf(acc1[nt][r]);
  }
  // dt=1 (covers tmp0 write->read latency)
#pragma unroll
  for (int nt = 0; nt < 5; ++nt) acc1[nt] = zf;
#pragma unroll
  for (int kk = 0; kk < 3; ++kk)
#pragma unroll
    for (int nt = 0; nt < 5; ++nt) {
      bf16x8 b = *reinterpret_cast<const bf16x8*>(&xraw[(25 + nt * 16 + l15) * XRS + kk * 32 + q8]);
      acc1[nt] = __builtin_amdgcn_mfma_f32_16x16x32_bf16(w[kk], b, acc1[nt], 0, 0, 0);
    }
#pragma unroll
  for (int nt = 0; nt < 5; ++nt) {
    int col = nt * 16 + l15;
#pragma unroll
    for (int r = 0; r < 4; ++r)
      tmp1[(row4 + r) * TMS + col] = f2bf(acc1[nt][r]);
  }
}

// ---------------- K1: t2 fused (MLP -> agg) x12 MFMA, pipelined weights -----
// grid = N*T/2 = 512 blocks, 384 threads (6 waves). Wave w owns o-rows [16w,16w+16).
__global__ __launch_bounds__(384, 3) void k1t2(
    const float* __restrict__ x, const unsigned short* __restrict__ ABsw,
    const unsigned short* __restrict__ Wsw, const float* __restrict__ bm,
    unsigned short* __restrict__ h_relu, float* __restrict__ stats1) {
  __shared__ unsigned short xraw[112 * XRS];     // rows r=tt_rel*25+v, 100..111 zero
  __shared__ unsigned short tmp_s[2][96 * TMS];  // per-dt tmp [o][u']
  __shared__ float st1s[96], st2s[96];
  const int tid = threadIdx.x;
  const int n = blockIdx.x >> 6, t0 = (blockIdx.x & 63) * 2;
  const int wave = tid >> 6, lane = tid & 63;
  const int l15 = lane & 15, quad = lane >> 4, q8 = quad * 8;
  const int wrow16 = wave * 16;
  const int row4 = wrow16 + quad * 4;

  // stage raw x slice: tt = t0-1 .. t0+2 (100 rows), zero-pad rows to 112
  for (int idx = tid; idx < 96 * 112; idx += 384) {
    int c = idx / 112, r = idx - c * 112;
    float v = 0.f;
    if (r < 100) {
      int tt = t0 - 1 + r / 25, vv = r % 25;
      if (tt >= 0 && tt < TB) v = x[((n * CB + c) * TB + tt) * VB + vv];
    }
    xraw[r * XRS + c] = f2bf(v);
  }
  // zero tmp K-pad cols [80,96) for both buffers
  for (int idx = tid; idx < 2 * 96 * 16; idx += 384) {
    int b = idx / (96 * 16), rem = idx - b * 96 * 16;
    tmp_s[b][(rem / 16) * TMS + 80 + rem % 16] = 0;
  }
  __syncthreads();

  const f32x4 zf = {0.f, 0.f, 0.f, 0.f};
  f32x4 acc2[2][5];
#pragma unroll
  for (int d = 0; d < 2; ++d)
#pragma unroll
    for (int nt = 0; nt < 5; ++nt) acc2[d][nt] = zf;

  const unsigned short* Wbase = Wsw + wave * 1536 + lane * 8;   // + ps*9216 + kk*512
  const unsigned short* Bbase = ABsw + lane * 8;                // + ps*7680 + (nt*3+kk)*512

  bf16x8 wa[3], bf[15];

  // prologue: weights(ps=0) + G1(0)
#pragma unroll
  for (int kk = 0; kk < 3; ++kk)
    wa[kk] = *reinterpret_cast<const bf16x8*>(Wbase + kk * 512);
#pragma unroll
  for (int i = 0; i < 15; ++i)
    bf[i] = *reinterpret_cast<const bf16x8*>(Bbase + i * 512);
  g1both_fn(xraw, tmp_s[0], tmp_s[1], wa[0], wa[1], wa[2], l15, q8, row4);

#pragma unroll
  for (int ps = 0; ps < 12; ++ps) {
    // issue wa(ps+1) — consumed by G1(ps+1) after G2's 30 MFMAs
    if (ps < 11) {
#pragma unroll
      for (int kk = 0; kk < 3; ++kk)
        wa[kk] = *reinterpret_cast<const bf16x8*>(Wbase + (ps + 1) * 9216 + kk * 512);
    }
    // GEMM2 both dt using bf(ps); reads tmp written by G1(ps)
#pragma unroll
    for (int kk = 0; kk < 3; ++kk) {
      bf16x8 a0 = *reinterpret_cast<const bf16x8*>(&tmp_s[0][(wrow16 + l15) * TMS + kk * 32 + q8]);
#pragma unroll
      for (int nt = 0; nt < 5; ++nt)
        acc2[0][nt] = __builtin_amdgcn_mfma_f32_16x16x32_bf16(a0, bf[nt * 3 + kk], acc2[0][nt], 0, 0, 0);
      bf16x8 a1 = *reinterpret_cast<const bf16x8*>(&tmp_s[1][(wrow16 + l15) * TMS + kk * 32 + q8]);
#pragma unroll
      for (int nt = 0; nt < 5; ++nt)
        acc2[1][nt] = __builtin_amdgcn_mfma_f32_16x16x32_bf16(a1, bf[nt * 3 + kk], acc2[1][nt], 0, 0, 0);
    }
    if (ps < 11) {
      // issue bf(ps+1) — consumed by G2(ps+1) after G1's 30 MFMAs
#pragma unroll
      for (int i = 0; i < 15; ++i)
        bf[i] = *reinterpret_cast<const bf16x8*>(Bbase + (ps + 1) * 7680 + i * 512);
      // G1(ps+1): overwrites tmp AFTER G2(ps)'s reads (same-wave DS ordering)
      g1both_fn(xraw, tmp_s[0], tmp_s[1], wa[0], wa[1], wa[2], l15, q8, row4);
    }
  }

  // epilogue: bias + relu + bf16 store (HR layout [n][t][o][u]) + BN1 stats
  float s1[4] = {0.f, 0.f, 0.f, 0.f}, s2[4] = {0.f, 0.f, 0.f, 0.f};
#pragma unroll
  for (int d = 0; d < 2; ++d) {
    const int t = t0 + d;
#pragma unroll
    for (int r = 0; r < 4; ++r) {
      const int o = row4 + r;
      const float bias = bm[o];
      unsigned short* hp = h_relu + ((n * TB + t) * CB + o) * VLB;
#pragma unroll
      for (int nt = 0; nt < 5; ++nt) {
        int u = nt * 16 + l15;
        if (u < VLB) {
          float v = acc2[d][nt][r] + bias;
          v = v > 0.f ? v : 0.f;
          hp[u] = f2bf(v);
          s1[r] += v;
          s2[r] += v * v;
        }
      }
    }
  }
#pragma unroll
  for (int off = 1; off < 16; off <<= 1) {
#pragma unroll
    for (int r = 0; r < 4; ++r) {
      s1[r] += __shfl_xor(s1[r], off, 64);
      s2[r] += __shfl_xor(s2[r], off, 64);
    }
  }
  if (l15 == 0) {
#pragma unroll
    for (int r = 0; r < 4; ++r) { st1s[row4 + r] = s1[r]; st2s[row4 + r] = s2[r]; }
  }
  __syncthreads();
  if (tid < 96) {
    atomicAdd(&stats1[tid], st1s[tid]);
    atomicAdd(&stats1[96 + tid], st2s[tid]);
  }
}

// ---------------- K3: BN1-finalize + relu + out_conv (MFMA, 1 t/blk) --------
// grid = N*T = 1024 blocks. HR is [n][t][o][u]: the block's whole input slice
// is 7200 contiguous bf16 -> 900 coalesced b128 loads. LDS 20.5KB -> 4 blk/CU.
__global__ __launch_bounds__(384, 4) void k3n(
    const unsigned short* __restrict__ h_relu, const float* __restrict__ stats1,
    const float* __restrict__ g1, const float* __restrict__ bt1,
    const unsigned short* __restrict__ Wosw, const float* __restrict__ bo,
    float* __restrict__ out_pre, float* __restrict__ stats2) {
  __shared__ unsigned short hnb[32 * HBS];
  __shared__ float a1s[96], b1s[96];
  __shared__ float st1[96], st2[96];
  const int tid = threadIdx.x;
  const int n = blockIdx.x >> 7, t = blockIdx.x & 127;

  if (tid < 96) {
    const float inv = 1.f / (8.f * 128.f * 75.f);
    float m = stats1[tid] * inv;
    float var = stats1[96 + tid] * inv - m * m;
    float a = g1[tid] * rsqrtf(var + EPSB);
    a1s[tid] = a;
    b1s[tid] = bt1[tid] - m * a;
  }
  for (int idx = tid; idx < 7 * HBS; idx += 384) hnb[25 * HBS + idx] = 0;
  __syncthreads();

  const unsigned short* hp = h_relu + (n * TB + t) * (CB * VLB);
  for (int i8 = tid; i8 < 900; i8 += 384) {
    bf16x8 v = *reinterpret_cast<const bf16x8*>(hp + i8 * 8);
    const int e = i8 * 8;
#pragma unroll
    for (int j = 0; j < 8; ++j) {
      int ee = e + j;
      int i = ee / 75, u = ee - i * 75;
      float val = a1s[i] * bf2f((unsigned short)v[j]) + b1s[i];
      val = val > 0.f ? val : 0.f;
      int w = u / 25, vv = u - w * 25;
      hnb[vv * HBS + i * 3 + w] = f2bf(val);
    }
  }
  __syncthreads();

  const int wave = tid >> 6, lane = tid & 63;
  const int l15 = lane & 15, quad = lane >> 4, q8 = quad * 8;
  const f32x4 zf = {0.f, 0.f, 0.f, 0.f};
  f32x4 acc[2] = {zf, zf};
  const unsigned short* Apw = Wosw + wave * 4608 + lane * 8;
#pragma unroll
  for (int kk = 0; kk < 9; ++kk) {
    bf16x8 a = *reinterpret_cast<const bf16x8*>(Apw + kk * 512);
    bf16x8 b0 = *reinterpret_cast<const bf16x8*>(&hnb[l15 * HBS + kk * 32 + q8]);
    bf16x8 b1 = *reinterpret_cast<const bf16x8*>(&hnb[(16 + l15) * HBS + kk * 32 + q8]);
    acc[0] = __builtin_amdgcn_mfma_f32_16x16x32_bf16(a, b0, acc[0], 0, 0, 0);
    acc[1] = __builtin_amdgcn_mfma_f32_16x16x32_bf16(a, b1, acc[1], 0, 0, 0);
  }

  const int orow = wave * 16 + quad * 4;
  float s1[4] = {0.f, 0.f, 0.f, 0.f}, s2[4] = {0.f, 0.f, 0.f, 0.f};
#pragma unroll
  for (int nt = 0; nt < 2; ++nt) {
    int v = nt * 16 + l15;
    if (v < VB) {
#pragma unroll
      for (int r = 0; r < 4; ++r) {
        const int o = orow + r;
        float val = acc[nt][r] + bo[o];
        out_pre[((n * CB + o) * TB + t) * VB + v] = val;
        s1[r] += val;
        s2[r] += val * val;
      }
    }
  }
#pragma unroll
  for (int off = 1; off < 16; off <<= 1) {
#pragma unroll
    for (int r = 0; r < 4; ++r) {
      s1[r] += __shfl_xor(s1[r], off, 64);
      s2[r] += __shfl_xor(s2[r], off, 64);
    }
  }
  if (l15 == 0) {
#pragma unroll
    for (int r = 0; r < 4; ++r) { st1[orow + r] = s1[r]; st2[orow + r] = s2[r]; }
  }
  __syncthreads();
  if (tid < 96) {
    atomicAdd(&stats2[tid], st1[tid]);
    atomicAdd(&stats2[96 + tid], st2[tid]);
  }
}

// ---------------- K5: BN2 finalize (float4 elementwise) ----------------
__global__ __launch_bounds__(256) void k5_bn2(
    const float* __restrict__ out_pre, const float* __restrict__ stats2,
    const float* __restrict__ g2, const float* __restrict__ bt2,
    float* __restrict__ out) {
  int idx = blockIdx.x * 256 + threadIdx.x;
  if (idx >= NB * CB * TB * VB / 4) return;
  int o = (idx / (TB * VB / 4)) % CB;
  const float inv = 1.f / (8.f * 128.f * 25.f);
  float m = stats2[o] * inv;
  float var = stats2[96 + o] * inv - m * m;
  float a = g2[o] * rsqrtf(var + EPSB);
  float b = bt2[o] - m * a;
  f32x4 vin = reinterpret_cast<const f32x4*>(out_pre)[idx];
  f32x4 vo;
#pragma unroll
  for (int j = 0; j < 4; ++j) vo[j] = a * vin[j] + b;
  reinterpret_cast<f32x4*>(out)[idx] = vo;
}

extern "C" void kernel_launch(void* const* d_in, const int* in_sizes, int n_in,
                              void* d_out, int out_size, void* d_ws, size_t ws_size,
                              hipStream_t stream) {
  const float* x   = (const float*)d_in[0];
  const float* As  = (const float*)d_in[1];
  const float* Bs  = (const float*)d_in[2];
  const float* Ar  = (const float*)d_in[3];
  const float* Wm  = (const float*)d_in[4];
  const float* bm  = (const float*)d_in[5];
  const float* g1  = (const float*)d_in[6];
  const float* bt1 = (const float*)d_in[7];
  const float* Wo  = (const float*)d_in[8];
  const float* bo  = (const float*)d_in[9];
  const float* g2  = (const float*)d_in[10];
  const float* bt2 = (const float*)d_in[11];
  float* out = (float*)d_out;

  char* base = (char*)d_ws;
  unsigned short* HR   = (unsigned short*)base;                  // 14,745,600 B
  float* out_pre       = (float*)(base + 14745600);              //  9,830,400 B
  unsigned short* ABsw = (unsigned short*)(base + 24576000);     //    184,320 B
  unsigned short* Wsw  = (unsigned short*)(base + 24760320);     //    221,184 B
  unsigned short* Wosw = (unsigned short*)(base + 24981504);     //     55,296 B
  float* stats         = (float*)(base + 25036800);              //      1,536 B
  float* stats1 = stats, *stats2 = stats + 192;

  k0_init<<<432, 256, 0, stream>>>(As, Bs, Ar, Wm, Wo, ABsw, Wsw, Wosw, stats);
  k1t2<<<NB * TB / 2, 384, 0, stream>>>(x, ABsw, Wsw, bm, HR, stats1);
  k3n<<<NB * TB, 384, 0, stream>>>(HR, stats1, g1, bt1, Wosw, bo, out_pre, stats2);
  k5_bn2<<<(NB * CB * TB * VB / 4 + 255) / 256, 256, 0, stream>>>(out_pre, stats2, g2, bt2, out);
}

// Round 3
// 182.713 us; speedup vs baseline: 1.6153x; 1.6135x over previous
//
#include <hip/hip_runtime.h>

// MS-G3D block. bf16-MFMA, t-chunk=2 fused k1 with fragment-swizzled weights.
// This rev: k1 restored VERBATIM to the 190µs-session body (rounds 1-2's
// rotated-pipeline variants triggered array->scratch demotion: 412MB scratch
// traffic, 2x slowdown). Only k1 change: HR layout [n][t][o][u] so k3 can
// stage its whole input slice with coalesced b128 loads. k3 rewritten:
// no stats tail (no shuffle rounds, no 512x192 same-address atomics);
// stats2 moved to k4, a dedicated coalesced 384-block reduction (4 RMW/addr).
// N=8, C=96, T=128, V=25, WIN=3, VL=75, NS=6.

#define NB 8
#define CB 96
#define TB 128
#define VB 25
#define VLB 75
#define EPSB 1e-5f
#define XRS 104   // xraw row stride (shorts)
#define TMS 104   // tmp row stride
#define HBS 296   // hnb row stride (shorts)

typedef __attribute__((ext_vector_type(8))) short bf16x8;
typedef __attribute__((ext_vector_type(4))) float f32x4;

__device__ inline unsigned short f2bf(float f) {
  unsigned int u = __float_as_uint(f);
  u = (u + 0x7FFFu + ((u >> 16) & 1u)) >> 16;
  return (unsigned short)u;
}
__device__ inline float bf2f(unsigned short u) {
  return __uint_as_float(((unsigned int)u) << 16);
}

// ---------------- K0: build fragment-swizzled bf16 weights; zero stats -------
// Wsw  [ps][wave][kk][lane][j] : W_ps[o=wave*16+(lane&15)][c=kk*32+(lane>>4)*8+j]
// ABsw [ps][nt][kk][lane][j]   : AB_ps[u=nt*16+(lane&15)][u'=kk*32+(lane>>4)*8+j]
// Wosw [wave][kk][lane][j]     : Wo[o=wave*16+(lane&15)][k=kk*32+(lane>>4)*8+j]
__global__ __launch_bounds__(256) void k0_init(
    const float* __restrict__ As, const float* __restrict__ Bs,
    const float* __restrict__ Ar, const float* __restrict__ Wm,
    const float* __restrict__ Wo,
    unsigned short* __restrict__ ABsw, unsigned short* __restrict__ Wsw,
    unsigned short* __restrict__ Wosw, float* __restrict__ stats) {
  int i = blockIdx.x * 256 + threadIdx.x;
  if (i < 110592) {                     // Wsw: 12*6*3*512
    int ps = i / 9216, r = i % 9216;
    int wv = r / 1536, r2 = r % 1536;
    int kk = r2 / 512, r3 = r2 % 512;
    int lane = r3 / 8, j = r3 % 8;
    int o = wv * 16 + (lane & 15);
    int c = kk * 32 + (lane >> 4) * 8 + j;
    Wsw[i] = f2bf(Wm[o * 1152 + ps * 96 + c]);
  }
  if (i < 92160) {                      // ABsw: 12*5*3*512
    int ps = i / 7680, r = i % 7680;
    int nt = r / 1536, r2 = r % 1536;
    int kk = r2 / 512, r3 = r2 % 512;
    int lane = r3 / 8, j = r3 % 8;
    int u = nt * 16 + (lane & 15);
    int up = kk * 32 + (lane >> 4) * 8 + j;
    float v = 0.f;
    if (u < 75 && up < 75) {
      int path = ps / 6, s = ps % 6;
      int idx = (s * 75 + u) * 75 + up;
      v = (path == 0 ? As[idx] : Bs[idx]) + Ar[idx];
    }
    ABsw[i] = f2bf(v);
  }
  if (i < 27648) {                      // Wosw: 6*9*512
    int wv = i / 4608, r = i % 4608;
    int kk = r / 512, r3 = r % 512;
    int lane = r3 / 8, j = r3 % 8;
    int o = wv * 16 + (lane & 15);
    int k = kk * 32 + (lane >> 4) * 8 + j;
    Wosw[i] = f2bf(Wo[o * 288 + k]);
  }
  if (i < 384) stats[i] = 0.f;
}

// ---------------- K1: t2 fused (MLP -> agg) x12 MFMA, swizzled weights -------
// grid = N*T/2 = 512 blocks, 384 threads (6 waves). Wave w owns o-rows [16w,16w+16).
// VERBATIM the verified 97µs body (loads at top of ps loop; compiler sinks
// them; VGPR 76, no scratch). Only the HR store index differs ([n][t][o][u]).
__global__ __launch_bounds__(384, 2) void k1t2(
    const float* __restrict__ x, const unsigned short* __restrict__ ABsw,
    const unsigned short* __restrict__ Wsw, const float* __restrict__ bm,
    unsigned short* __restrict__ h_relu, float* __restrict__ stats1) {
  __shared__ unsigned short xraw[112 * XRS];     // rows r=tt_rel*25+v, 100..111 zero
  __shared__ unsigned short tmp_s[2][96 * TMS];  // per-dt tmp [o][u']
  __shared__ float st1s[96], st2s[96];
  const int tid = threadIdx.x;
  const int n = blockIdx.x >> 6, t0 = (blockIdx.x & 63) * 2;
  const int wave = tid >> 6, lane = tid & 63;
  const int l15 = lane & 15, quad = lane >> 4, q8 = quad * 8;
  const int wrow16 = wave * 16;

  // stage raw x slice: tt = t0-1 .. t0+2 (100 rows), zero-pad rows to 112
  for (int idx = tid; idx < 96 * 112; idx += 384) {
    int c = idx / 112, r = idx - c * 112;
    float v = 0.f;
    if (r < 100) {
      int tt = t0 - 1 + r / 25, vv = r % 25;
      if (tt >= 0 && tt < TB) v = x[((n * CB + c) * TB + tt) * VB + vv];
    }
    xraw[r * XRS + c] = f2bf(v);
  }
  // zero tmp K-pad cols [80,96) for both buffers (cols 75..79 written 0 each ps)
  for (int idx = tid; idx < 2 * 96 * 16; idx += 384) {
    int b = idx / (96 * 16), rem = idx - b * 96 * 16;
    tmp_s[b][(rem / 16) * TMS + 80 + rem % 16] = 0;
  }
  __syncthreads();

  const f32x4 zf = {0.f, 0.f, 0.f, 0.f};
  f32x4 acc2[2][5];
#pragma unroll
  for (int d = 0; d < 2; ++d)
#pragma unroll
    for (int nt = 0; nt < 5; ++nt) acc2[d][nt] = zf;

  const unsigned short* Wbase = Wsw + wave * 1536 + lane * 8;   // + ps*9216 + kk*512
  const unsigned short* Bbase = ABsw + lane * 8;                // + ps*7680 + (nt*3+kk)*512

#pragma unroll
  for (int ps = 0; ps < 12; ++ps) {
    // coalesced fragment loads (dwordx4, lane-contiguous)
    bf16x8 wa[3];
#pragma unroll
    for (int kk = 0; kk < 3; ++kk)
      wa[kk] = *reinterpret_cast<const bf16x8*>(Wbase + ps * 9216 + kk * 512);
    bf16x8 bf[15];
#pragma unroll
    for (int i = 0; i < 15; ++i)
      bf[i] = *reinterpret_cast<const bf16x8*>(Bbase + ps * 7680 + i * 512);

    // GEMM1 dt=0
    f32x4 acc1[5];
#pragma unroll
    for (int nt = 0; nt < 5; ++nt) acc1[nt] = zf;
#pragma unroll
    for (int kk = 0; kk < 3; ++kk)
#pragma unroll
      for (int nt = 0; nt < 5; ++nt) {
        bf16x8 b = *reinterpret_cast<const bf16x8*>(&xraw[(nt * 16 + l15) * XRS + kk * 32 + q8]);
        acc1[nt] = __builtin_amdgcn_mfma_f32_16x16x32_bf16(wa[kk], b, acc1[nt], 0, 0, 0);
      }
#pragma unroll
    for (int nt = 0; nt < 5; ++nt) {
      int col = nt * 16 + l15;
#pragma unroll
      for (int r = 0; r < 4; ++r) {
        unsigned short v = (col < 75) ? f2bf(acc1[nt][r]) : (unsigned short)0;
        tmp_s[0][(wrow16 + quad * 4 + r) * TMS + col] = v;
      }
    }
    // GEMM1 dt=1 (covers tmp0 write->read latency)
#pragma unroll
    for (int nt = 0; nt < 5; ++nt) acc1[nt] = zf;
#pragma unroll
    for (int kk = 0; kk < 3; ++kk)
#pragma unroll
      for (int nt = 0; nt < 5; ++nt) {
        bf16x8 b = *reinterpret_cast<const bf16x8*>(&xraw[(25 + nt * 16 + l15) * XRS + kk * 32 + q8]);
        acc1[nt] = __builtin_amdgcn_mfma_f32_16x16x32_bf16(wa[kk], b, acc1[nt], 0, 0, 0);
      }
#pragma unroll
    for (int nt = 0; nt < 5; ++nt) {
      int col = nt * 16 + l15;
#pragma unroll
      for (int r = 0; r < 4; ++r) {
        unsigned short v = (col < 75) ? f2bf(acc1[nt][r]) : (unsigned short)0;
        tmp_s[1][(wrow16 + quad * 4 + r) * TMS + col] = v;
      }
    }

    // GEMM2 both dt; b-frags (registers) shared across dt
#pragma unroll
    for (int kk = 0; kk < 3; ++kk) {
      bf16x8 a0 = *reinterpret_cast<const bf16x8*>(&tmp_s[0][(wrow16 + l15) * TMS + kk * 32 + q8]);
#pragma unroll
      for (int nt = 0; nt < 5; ++nt)
        acc2[0][nt] = __builtin_amdgcn_mfma_f32_16x16x32_bf16(a0, bf[nt * 3 + kk], acc2[0][nt], 0, 0, 0);
      bf16x8 a1 = *reinterpret_cast<const bf16x8*>(&tmp_s[1][(wrow16 + l15) * TMS + kk * 32 + q8]);
#pragma unroll
      for (int nt = 0; nt < 5; ++nt)
        acc2[1][nt] = __builtin_amdgcn_mfma_f32_16x16x32_bf16(a1, bf[nt * 3 + kk], acc2[1][nt], 0, 0, 0);
    }
  }

  // epilogue: bias + relu + bf16 store + BN1 partial stats (both dt)
  const int orow = wrow16 + quad * 4;
  float s1[4] = {0.f, 0.f, 0.f, 0.f}, s2[4] = {0.f, 0.f, 0.f, 0.f};
#pragma unroll
  for (int d = 0; d < 2; ++d) {
    const int t = t0 + d;
#pragma unroll
    for (int r = 0; r < 4; ++r) {
      const int o = orow + r;
      const float bias = bm[o];
      unsigned short* hp = h_relu + ((n * TB + t) * CB + o) * VLB;
#pragma unroll
      for (int nt = 0; nt < 5; ++nt) {
        int u = nt * 16 + l15;
        if (u < VLB) {
          float v = acc2[d][nt][r] + bias;
          v = v > 0.f ? v : 0.f;
          hp[u] = f2bf(v);
          s1[r] += v;
          s2[r] += v * v;
        }
      }
    }
  }
#pragma unroll
  for (int off = 1; off < 16; off <<= 1) {
#pragma unroll
    for (int r = 0; r < 4; ++r) {
      s1[r] += __shfl_xor(s1[r], off, 64);
      s2[r] += __shfl_xor(s2[r], off, 64);
    }
  }
  if (l15 == 0) {
#pragma unroll
    for (int r = 0; r < 4; ++r) { st1s[orow + r] = s1[r]; st2s[orow + r] = s2[r]; }
  }
  __syncthreads();
  if (tid < 96) {
    atomicAdd(&stats1[tid], st1s[tid]);
    atomicAdd(&stats1[96 + tid], st2s[tid]);
  }
}

// ---------------- K3: BN1-finalize + relu + out_conv (MFMA, 2 t/blk) --------
// grid = N*T/2 = 512 blocks. HR is [n][t][o][u]: the block's input slice is
// 14400 contiguous bf16 -> 1800 coalesced b128 loads. No stats tail (stats2
// moved to k4). LDS 38.7KB -> 4 blocks/CU.
__global__ __launch_bounds__(384) void k3n(
    const unsigned short* __restrict__ h_relu, const float* __restrict__ stats1,
    const float* __restrict__ g1, const float* __restrict__ bt1,
    const unsigned short* __restrict__ Wosw, const float* __restrict__ bo,
    float* __restrict__ out_pre) {
  __shared__ unsigned short hnb[2][32 * HBS];
  __shared__ float a1s[96], b1s[96];
  const int tid = threadIdx.x;
  const int n = blockIdx.x >> 6, t0 = (blockIdx.x & 63) * 2;

  if (tid < 96) {
    const float inv = 1.f / (8.f * 128.f * 75.f);
    float m = stats1[tid] * inv;
    float var = stats1[96 + tid] * inv - m * m;
    float a = g1[tid] * rsqrtf(var + EPSB);
    a1s[tid] = a;
    b1s[tid] = bt1[tid] - m * a;
  }
  for (int idx = tid; idx < 2 * 7 * HBS; idx += 384) {
    int d = idx / (7 * HBS), rm = idx % (7 * HBS);
    hnb[d][25 * HBS + rm] = 0;
  }
  __syncthreads();

  // stage both t-slices: 14400 contiguous shorts, b128 loads, scatter to hnb
  const unsigned short* hp = h_relu + (n * TB + t0) * (CB * VLB);
  for (int i8 = tid; i8 < 1800; i8 += 384) {
    bf16x8 v = *reinterpret_cast<const bf16x8*>(hp + i8 * 8);
    int ee = i8 * 8;
    int d = (ee >= 7200) ? 1 : 0;
    int rem = ee - d * 7200;          // group never straddles (7200 % 8 == 0)
#pragma unroll
    for (int j = 0; j < 8; ++j) {
      int e = rem + j;
      int i = e / 75, u = e - i * 75;
      float val = a1s[i] * bf2f((unsigned short)v[j]) + b1s[i];
      val = val > 0.f ? val : 0.f;
      int w = u / 25, vv = u - w * 25;
      hnb[d][vv * HBS + i * 3 + w] = f2bf(val);
    }
  }
  __syncthreads();

  const int wave = tid >> 6, lane = tid & 63;
  const int l15 = lane & 15, quad = lane >> 4, q8 = quad * 8;
  const f32x4 zf = {0.f, 0.f, 0.f, 0.f};
  f32x4 acc[2][2] = {{zf, zf}, {zf, zf}};
  const unsigned short* Apw = Wosw + wave * 4608 + lane * 8;
#pragma unroll
  for (int kk = 0; kk < 9; ++kk) {
    bf16x8 a = *reinterpret_cast<const bf16x8*>(Apw + kk * 512);
#pragma unroll
    for (int d = 0; d < 2; ++d) {
      bf16x8 b0 = *reinterpret_cast<const bf16x8*>(&hnb[d][l15 * HBS + kk * 32 + q8]);
      bf16x8 b1 = *reinterpret_cast<const bf16x8*>(&hnb[d][(16 + l15) * HBS + kk * 32 + q8]);
      acc[d][0] = __builtin_amdgcn_mfma_f32_16x16x32_bf16(a, b0, acc[d][0], 0, 0, 0);
      acc[d][1] = __builtin_amdgcn_mfma_f32_16x16x32_bf16(a, b1, acc[d][1], 0, 0, 0);
    }
  }

  const int orow = wave * 16 + quad * 4;
#pragma unroll
  for (int d = 0; d < 2; ++d) {
#pragma unroll
    for (int nt = 0; nt < 2; ++nt) {
      int v = nt * 16 + l15;
      if (v < VB) {
#pragma unroll
        for (int r = 0; r < 4; ++r) {
          const int o = orow + r;
          out_pre[((n * CB + o) * TB + t0 + d) * VB + v] = acc[d][nt][r] + bo[o];
        }
      }
    }
  }
}

// ---------------- K4: BN2 stats (coalesced float4 reduction) ----------------
// grid = 96*4: block (o, part p over n-pairs). out_pre[n][o][t][v] slabs are
// contiguous 12800B -> float4 loads. 4 atomic RMWs per stats address total.
__global__ __launch_bounds__(256) void k4_stats(
    const float* __restrict__ out_pre, float* __restrict__ stats2) {
  __shared__ float ws1[4], ws2[4];
  const int tid = threadIdx.x;
  const int o = blockIdx.x % CB, p = blockIdx.x / CB;
  float s1 = 0.f, s2 = 0.f;
#pragma unroll
  for (int k = 0; k < 2; ++k) {
    const int n = 2 * p + k;
    const f32x4* base = reinterpret_cast<const f32x4*>(out_pre + (n * CB + o) * (TB * VB));
    for (int idx = tid; idx < TB * VB / 4; idx += 256) {
      f32x4 v = base[idx];
#pragma unroll
      for (int j = 0; j < 4; ++j) { s1 += v[j]; s2 += v[j] * v[j]; }
    }
  }
#pragma unroll
  for (int off = 1; off < 64; off <<= 1) {
    s1 += __shfl_xor(s1, off, 64);
    s2 += __shfl_xor(s2, off, 64);
  }
  const int wave = tid >> 6;
  if ((tid & 63) == 0) { ws1[wave] = s1; ws2[wave] = s2; }
  __syncthreads();
  if (tid == 0) {
    float r1 = ws1[0] + ws1[1] + ws1[2] + ws1[3];
    float r2 = ws2[0] + ws2[1] + ws2[2] + ws2[3];
    atomicAdd(&stats2[o], r1);
    atomicAdd(&stats2[96 + o], r2);
  }
}

// ---------------- K5: BN2 finalize (float4 elementwise) ----------------
__global__ __launch_bounds__(256) void k5_bn2(
    const float* __restrict__ out_pre, const float* __restrict__ stats2,
    const float* __restrict__ g2, const float* __restrict__ bt2,
    float* __restrict__ out) {
  int idx = blockIdx.x * 256 + threadIdx.x;
  if (idx >= NB * CB * TB * VB / 4) return;
  int o = (idx / (TB * VB / 4)) % CB;
  const float inv = 1.f / (8.f * 128.f * 25.f);
  float m = stats2[o] * inv;
  float var = stats2[96 + o] * inv - m * m;
  float a = g2[o] * rsqrtf(var + EPSB);
  float b = bt2[o] - m * a;
  f32x4 vin = reinterpret_cast<const f32x4*>(out_pre)[idx];
  f32x4 vo;
#pragma unroll
  for (int j = 0; j < 4; ++j) vo[j] = a * vin[j] + b;
  reinterpret_cast<f32x4*>(out)[idx] = vo;
}

extern "C" void kernel_launch(void* const* d_in, const int* in_sizes, int n_in,
                              void* d_out, int out_size, void* d_ws, size_t ws_size,
                              hipStream_t stream) {
  const float* x   = (const float*)d_in[0];
  const float* As  = (const float*)d_in[1];
  const float* Bs  = (const float*)d_in[2];
  const float* Ar  = (const float*)d_in[3];
  const float* Wm  = (const float*)d_in[4];
  const float* bm  = (const float*)d_in[5];
  const float* g1  = (const float*)d_in[6];
  const float* bt1 = (const float*)d_in[7];
  const float* Wo  = (const float*)d_in[8];
  const float* bo  = (const float*)d_in[9];
  const float* g2  = (const float*)d_in[10];
  const float* bt2 = (const float*)d_in[11];
  float* out = (float*)d_out;

  char* base = (char*)d_ws;
  unsigned short* HR   = (unsigned short*)base;                  // 14,745,600 B
  float* out_pre       = (float*)(base + 14745600);              //  9,830,400 B
  unsigned short* ABsw = (unsigned short*)(base + 24576000);     //    184,320 B
  unsigned short* Wsw  = (unsigned short*)(base + 24760320);     //    221,184 B
  unsigned short* Wosw = (unsigned short*)(base + 24981504);     //     55,296 B
  float* stats         = (float*)(base + 25036800);              //      1,536 B
  float* stats1 = stats, *stats2 = stats + 192;

  k0_init<<<432, 256, 0, stream>>>(As, Bs, Ar, Wm, Wo, ABsw, Wsw, Wosw, stats);
  k1t2<<<NB * TB / 2, 384, 0, stream>>>(x, ABsw, Wsw, bm, HR, stats1);
  k3n<<<NB * TB / 2, 384, 0, stream>>>(HR, stats1, g1, bt1, Wosw, bo, out_pre);
  k4_stats<<<CB * 4, 256, 0, stream>>>(out_pre, stats2);
  k5_bn2<<<(NB * CB * TB * VB / 4 + 255) / 256, 256, 0, stream>>>(out_pre, stats2, g2, bt2, out);
}

// Round 8
// 180.282 us; speedup vs baseline: 1.6371x; 1.0135x over previous
//
#include <hip/hip_runtime.h>

// MS-G3D block. bf16-MFMA, t-chunk=2 fused k1.
// Round-7 structure (swapped-GEMM1 -> transposed tmp2, vector LDS handoff,
// TBAA-safe short-family stores + fences) with ONE change: all
// v_cvt_pk_bf16_f32 packing replaced by manual f2bf|f2bf<<16 integer packing.
// Rounds 5/6/7 (three different k1 mechanisms) all failed at absmax~5.2 and
// all shared cvt_pk -- its lo/hi operand order is the only assumption never
// exercised by a passing kernel. Bisect: remove it.
//  - GEMM1 SWAPPED: mfma(x_frag, W_frag) -> D' = tmp^T; lane holds o=l15,
//    4 consecutive u' -> ONE ds_write_b64 per nt into tmp2[o][u'].
//  - GEMM2 original proven orientation: A = b128 tmp2[l15][kk*32+q8], B = ABsw.
//  - k1 stores HR in k3's hnb layout [n][t][vv][i*3+w]; k3 stages linearly.
// N=8, C=96, T=128, V=25, WIN=3, VL=75, NS=6.

#define NB 8
#define CB 96
#define TB 128
#define VB 25
#define VLB 75
#define EPSB 1e-5f
#define XRS 104   // xraw row stride (shorts)
#define T2S 104   // tmp2 row stride (shorts)
#define HBS 296   // hnb row stride (shorts)

typedef __attribute__((ext_vector_type(8))) short bf16x8;
typedef __attribute__((ext_vector_type(4))) short short4v;
typedef __attribute__((ext_vector_type(4))) float f32x4;
typedef __attribute__((ext_vector_type(2))) unsigned int uint2v;
typedef __attribute__((ext_vector_type(4))) unsigned int uint4v;

__device__ inline unsigned short f2bf(float f) {
  unsigned int u = __float_as_uint(f);
  u = (u + 0x7FFFu + ((u >> 16) & 1u)) >> 16;
  return (unsigned short)u;
}
__device__ inline float bf2f(unsigned short u) {
  return __uint_as_float(((unsigned int)u) << 16);
}
__device__ inline unsigned pack2bf(float lo, float hi) {
  return (unsigned)f2bf(lo) | ((unsigned)f2bf(hi) << 16);
}

// ---------------- K0: build fragment-swizzled bf16 weights; zero stats -------
// Wsw  [ps][wave][kk][lane][j] : W_ps[o=wv*16+(l&15)][c=kk*32+(l>>4)*8+j]
// ABsw [ps][nt][kk][lane][j]   : AB_ps[u=nt*16+(l&15)][u'=kk*32+(l>>4)*8+j]  (STANDARD)
// Wosw [wave][kk][lane][j]     : Wo[o=wv*16+(l&15)][k=kk*32+(l>>4)*8+j]
__global__ __launch_bounds__(256) void k0_init(
    const float* __restrict__ As, const float* __restrict__ Bs,
    const float* __restrict__ Ar, const float* __restrict__ Wm,
    const float* __restrict__ Wo,
    unsigned short* __restrict__ ABsw, unsigned short* __restrict__ Wsw,
    unsigned short* __restrict__ Wosw, float* __restrict__ stats) {
  int i = blockIdx.x * 256 + threadIdx.x;
  if (i < 110592) {                     // Wsw: 12*6*3*512
    int ps = i / 9216, r = i % 9216;
    int wv = r / 1536, r2 = r % 1536;
    int kk = r2 / 512, r3 = r2 % 512;
    int lane = r3 / 8, j = r3 % 8;
    int o = wv * 16 + (lane & 15);
    int c = kk * 32 + (lane >> 4) * 8 + j;
    Wsw[i] = f2bf(Wm[o * 1152 + ps * 96 + c]);
  }
  if (i < 92160) {                      // ABsw: 12*5*3*512
    int ps = i / 7680, r = i % 7680;
    int nt = r / 1536, r2 = r % 1536;
    int kk = r2 / 512, r3 = r2 % 512;
    int lane = r3 / 8, j = r3 % 8;
    int u = nt * 16 + (lane & 15);
    int up = kk * 32 + (lane >> 4) * 8 + j;
    float v = 0.f;
    if (u < 75 && up < 75) {
      int path = ps / 6, s = ps % 6;
      int idx = (s * 75 + u) * 75 + up;
      v = (path == 0 ? As[idx] : Bs[idx]) + Ar[idx];
    }
    ABsw[i] = f2bf(v);
  }
  if (i < 27648) {                      // Wosw: 6*9*512
    int wv = i / 4608, r = i % 4608;
    int kk = r / 512, r3 = r % 512;
    int lane = r3 / 8, j = r3 % 8;
    int o = wv * 16 + (lane & 15);
    int k = kk * 32 + (lane >> 4) * 8 + j;
    Wosw[i] = f2bf(Wo[o * 288 + k]);
  }
  if (i < 384) stats[i] = 0.f;
}

// ---------------- K1: t2 fused (MLP -> agg) x12 MFMA --------------------------
// grid = N*T/2 = 512 blocks, 384 threads (6 waves). Wave w owns o [16w,16w+16).
__global__ __launch_bounds__(384, 2) void k1t2(
    const float* __restrict__ x, const unsigned short* __restrict__ ABsw,
    const unsigned short* __restrict__ Wsw, const float* __restrict__ bm,
    unsigned short* __restrict__ h_relu, float* __restrict__ stats1) {
  __shared__ unsigned short xraw[112 * XRS];      // rows r=tt_rel*25+v, 100..111 zero
  __shared__ unsigned short tmp2[6][2][16 * T2S]; // [wave][dt][o16][u' 0..103]
  __shared__ float st1s[96], st2s[96];
  const int tid = threadIdx.x;
  const int n = blockIdx.x >> 6, t0 = (blockIdx.x & 63) * 2;
  const int wave = tid >> 6, lane = tid & 63;
  const int l15 = lane & 15, quad = lane >> 4, q8 = quad * 8;
  const int wrow16 = wave * 16;

  // stage raw x slice: tt = t0-1 .. t0+2 (100 rows), zero-pad rows to 112
  for (int idx = tid; idx < 96 * 112; idx += 384) {
    int c = idx / 112, r = idx - c * 112;
    float v = 0.f;
    if (r < 100) {
      int tt = t0 - 1 + r / 25, vv = r % 25;
      if (tt >= 0 && tt < TB) v = x[((n * CB + c) * TB + tt) * VB + vv];
    }
    xraw[r * XRS + c] = f2bf(v);
  }
  // zero tmp2 cols u' in [80,96): never written by GEMM1 (nt<=4 covers u'<80)
  // but read by GEMM2 kk=2 (u' 64..95). ABsw cols u'>=75 are zero, but
  // uninitialized LDS could be NaN -> NaN*0 = NaN; must zero.
  for (int idx = tid; idx < 6 * 2 * 256; idx += 384) {
    int w = idx >> 9, rm = idx & 511;
    int d = rm >> 8, e = rm & 255;        // e = o*16 + (u'-80)
    tmp2[w][d][(e >> 4) * T2S + 80 + (e & 15)] = 0;
  }
  __syncthreads();

  const f32x4 zf = {0.f, 0.f, 0.f, 0.f};
  f32x4 acc2[2][5];   // [dt][nt]: D[o][u], lane: u = nt*16+l15, o = 16w+4q+r
#pragma unroll
  for (int d = 0; d < 2; ++d)
#pragma unroll
    for (int nt = 0; nt < 5; ++nt) acc2[d][nt] = zf;

  const unsigned short* Wbase = Wsw + wave * 1536 + lane * 8;   // + ps*9216 + kk*512
  const unsigned short* Bbase = ABsw + lane * 8;                // + ps*7680 + (nt*3+kk)*512
  // GEMM1' store base: tmp2[wave][dt][l15*T2S + nt*16 + 4q] (b64, 8B-aligned)
  unsigned short* tw0 = &tmp2[wave][0][l15 * T2S + quad * 4];
  unsigned short* tw1 = &tmp2[wave][1][l15 * T2S + quad * 4];
  // GEMM2 read base: tmp2[wave][dt][l15*T2S + kk*32 + q8] (b128, 16B-aligned)
  const unsigned short* tr0 = &tmp2[wave][0][l15 * T2S + q8];
  const unsigned short* tr1 = &tmp2[wave][1][l15 * T2S + q8];

#pragma unroll
  for (int ps = 0; ps < 12; ++ps) {
    bf16x8 wa[3];
#pragma unroll
    for (int kk = 0; kk < 3; ++kk)
      wa[kk] = *reinterpret_cast<const bf16x8*>(Wbase + ps * 9216 + kk * 512);
    bf16x8 bf[15];
#pragma unroll
    for (int i = 0; i < 15; ++i)
      bf[i] = *reinterpret_cast<const bf16x8*>(Bbase + ps * 7680 + i * 512);

    // GEMM1' dt=0 (SWAPPED operands): D'[u'][o16], u' = nt*16+4q+r, o16 = l15
    f32x4 acc1[5];
#pragma unroll
    for (int nt = 0; nt < 5; ++nt) acc1[nt] = zf;
#pragma unroll
    for (int kk = 0; kk < 3; ++kk)
#pragma unroll
      for (int nt = 0; nt < 5; ++nt) {
        bf16x8 a = *reinterpret_cast<const bf16x8*>(&xraw[(nt * 16 + l15) * XRS + kk * 32 + q8]);
        acc1[nt] = __builtin_amdgcn_mfma_f32_16x16x32_bf16(a, wa[kk], acc1[nt], 0, 0, 0);
      }
#pragma unroll
    for (int nt = 0; nt < 5; ++nt) {
      // manual packing: r0 in low half, r1 in high half (unambiguous)
      unsigned p01 = pack2bf(acc1[nt][0], acc1[nt][1]);
      unsigned p23 = pack2bf(acc1[nt][2], acc1[nt][3]);
      *reinterpret_cast<short4v*>(tw0 + nt * 16) =
          __builtin_bit_cast(short4v, (uint2v){p01, p23});
    }
    // GEMM1' dt=1
#pragma unroll
    for (int nt = 0; nt < 5; ++nt) acc1[nt] = zf;
#pragma unroll
    for (int kk = 0; kk < 3; ++kk)
#pragma unroll
      for (int nt = 0; nt < 5; ++nt) {
        bf16x8 a = *reinterpret_cast<const bf16x8*>(&xraw[(25 + nt * 16 + l15) * XRS + kk * 32 + q8]);
        acc1[nt] = __builtin_amdgcn_mfma_f32_16x16x32_bf16(a, wa[kk], acc1[nt], 0, 0, 0);
      }
#pragma unroll
    for (int nt = 0; nt < 5; ++nt) {
      unsigned p01 = pack2bf(acc1[nt][0], acc1[nt][1]);
      unsigned p23 = pack2bf(acc1[nt][2], acc1[nt][3]);
      *reinterpret_cast<short4v*>(tw1 + nt * 16) =
          __builtin_bit_cast(short4v, (uint2v){p01, p23});
    }

    // RAW fence: tmp2 writes complete (program order) before GEMM2 reads.
    asm volatile("" ::: "memory");
    __builtin_amdgcn_sched_barrier(0);

    // GEMM2 (original orientation, baseline-proven): D[o][u] += tmp[o][u'] AB[u][u']
#pragma unroll
    for (int kk = 0; kk < 3; ++kk) {
      bf16x8 a0 = *reinterpret_cast<const bf16x8*>(tr0 + kk * 32);
#pragma unroll
      for (int nt = 0; nt < 5; ++nt)
        acc2[0][nt] = __builtin_amdgcn_mfma_f32_16x16x32_bf16(a0, bf[nt * 3 + kk], acc2[0][nt], 0, 0, 0);
      bf16x8 a1 = *reinterpret_cast<const bf16x8*>(tr1 + kk * 32);
#pragma unroll
      for (int nt = 0; nt < 5; ++nt)
        acc2[1][nt] = __builtin_amdgcn_mfma_f32_16x16x32_bf16(a1, bf[nt * 3 + kk], acc2[1][nt], 0, 0, 0);
    }

    // WAR fence: next iteration's tmp2 writes must not hoist above these reads.
    asm volatile("" ::: "memory");
    __builtin_amdgcn_sched_barrier(0);
  }

  // epilogue (round-3-proven form): o = 16w+4q+r rows in regs, u = nt*16+l15.
  // HR layout = hnb layout: [n][t][vv][i*3+w], slice 7200 shorts per t.
  const int orow = wrow16 + quad * 4;
  float s1[4] = {0.f, 0.f, 0.f, 0.f}, s2[4] = {0.f, 0.f, 0.f, 0.f};
  unsigned short* hp = h_relu + (unsigned)(n * TB + t0) * 7200;
#pragma unroll
  for (int d = 0; d < 2; ++d) {
#pragma unroll
    for (int r = 0; r < 4; ++r) {
      const int o = orow + r;
      const float bias = bm[o];
#pragma unroll
      for (int nt = 0; nt < 5; ++nt) {
        int u = nt * 16 + l15;
        if (u < VLB) {
          float v = acc2[d][nt][r] + bias;
          v = v > 0.f ? v : 0.f;
          int w = u / 25, vv = u - w * 25;
          hp[d * 7200 + vv * 288 + o * 3 + w] = f2bf(v);
          s1[r] += v;
          s2[r] += v * v;
        }
      }
    }
  }
#pragma unroll
  for (int off = 1; off < 16; off <<= 1) {
#pragma unroll
    for (int r = 0; r < 4; ++r) {
      s1[r] += __shfl_xor(s1[r], off, 64);
      s2[r] += __shfl_xor(s2[r], off, 64);
    }
  }
  if (l15 == 0) {
#pragma unroll
    for (int r = 0; r < 4; ++r) { st1s[orow + r] = s1[r]; st2s[orow + r] = s2[r]; }
  }
  __syncthreads();
  if (tid < 96) {
    atomicAdd(&stats1[tid], st1s[tid]);
    atomicAdd(&stats1[96 + tid], st2s[tid]);
  }
}

// ---------------- K3: BN1-finalize + relu + out_conv (MFMA, 2 t/blk) --------
// grid = N*T/2 = 512 blocks. HR is already in hnb layout: staging is a linear
// b128-load -> BN+relu -> b128 LDS-write copy (no scatter). The uint4v LDS
// stores here cross a __syncthreads() before the short-family reads -> safe.
__global__ __launch_bounds__(384) void k3n(
    const unsigned short* __restrict__ h_relu, const float* __restrict__ stats1,
    const float* __restrict__ g1, const float* __restrict__ bt1,
    const unsigned short* __restrict__ Wosw, const float* __restrict__ bo,
    float* __restrict__ out_pre) {
  __shared__ unsigned short hnb[2][32 * HBS];
  __shared__ float a1s[96], b1s[96];
  const int tid = threadIdx.x;
  const int n = blockIdx.x >> 6, t0 = (blockIdx.x & 63) * 2;

  if (tid < 96) {
    const float inv = 1.f / (8.f * 128.f * 75.f);
    float m = stats1[tid] * inv;
    float var = stats1[96 + tid] * inv - m * m;
    float a = g1[tid] * rsqrtf(var + EPSB);
    a1s[tid] = a;
    b1s[tid] = bt1[tid] - m * a;
  }
  for (int idx = tid; idx < 2 * 7 * HBS; idx += 384) {
    int d = idx / (7 * HBS), rm = idx % (7 * HBS);
    hnb[d][25 * HBS + rm] = 0;
  }
  __syncthreads();

  // linear staging: 14400 contiguous shorts; 288 % 8 == 0 so a b128 group
  // never straddles an hnb row; (vv*HBS + c)*2 is 16B-aligned (HBS=296=37*8).
  const unsigned short* hp = h_relu + (unsigned)(n * TB + t0) * 7200;
  for (int i8 = tid; i8 < 1800; i8 += 384) {
    bf16x8 v = *reinterpret_cast<const bf16x8*>(hp + i8 * 8);
    int e = i8 * 8;
    int d = e / 7200;
    int er = e - d * 7200;
    int vv = er / 288, c = er - vv * 288;
    float f[8];
#pragma unroll
    for (int j = 0; j < 8; ++j) {
      int ic = (c + j) / 3;
      float val = a1s[ic] * bf2f((unsigned short)v[j]) + b1s[ic];
      f[j] = val > 0.f ? val : 0.f;
    }
    unsigned dw0 = pack2bf(f[0], f[1]);
    unsigned dw1 = pack2bf(f[2], f[3]);
    unsigned dw2 = pack2bf(f[4], f[5]);
    unsigned dw3 = pack2bf(f[6], f[7]);
    *reinterpret_cast<uint4v*>(&hnb[d][vv * HBS + c]) = (uint4v){dw0, dw1, dw2, dw3};
  }
  __syncthreads();

  const int wave = tid >> 6, lane = tid & 63;
  const int l15 = lane & 15, quad = lane >> 4, q8 = quad * 8;
  const f32x4 zf = {0.f, 0.f, 0.f, 0.f};
  f32x4 acc[2][2] = {{zf, zf}, {zf, zf}};
  const unsigned short* Apw = Wosw + wave * 4608 + lane * 8;
#pragma unroll
  for (int kk = 0; kk < 9; ++kk) {
    bf16x8 a = *reinterpret_cast<const bf16x8*>(Apw + kk * 512);
#pragma unroll
    for (int d = 0; d < 2; ++d) {
      bf16x8 b0 = *reinterpret_cast<const bf16x8*>(&hnb[d][l15 * HBS + kk * 32 + q8]);
      bf16x8 b1 = *reinterpret_cast<const bf16x8*>(&hnb[d][(16 + l15) * HBS + kk * 32 + q8]);
      acc[d][0] = __builtin_amdgcn_mfma_f32_16x16x32_bf16(a, b0, acc[d][0], 0, 0, 0);
      acc[d][1] = __builtin_amdgcn_mfma_f32_16x16x32_bf16(a, b1, acc[d][1], 0, 0, 0);
    }
  }

  const int orow = wave * 16 + quad * 4;
#pragma unroll
  for (int d = 0; d < 2; ++d) {
#pragma unroll
    for (int nt = 0; nt < 2; ++nt) {
      int v = nt * 16 + l15;
      if (v < VB) {
#pragma unroll
        for (int r = 0; r < 4; ++r) {
          const int o = orow + r;
          out_pre[((n * CB + o) * TB + t0 + d) * VB + v] = acc[d][nt][r] + bo[o];
        }
      }
    }
  }
}

// ---------------- K4: BN2 stats (coalesced float4 reduction) ----------------
__global__ __launch_bounds__(256) void k4_stats(
    const float* __restrict__ out_pre, float* __restrict__ stats2) {
  __shared__ float ws1[4], ws2[4];
  const int tid = threadIdx.x;
  const int o = blockIdx.x % CB, p = blockIdx.x / CB;
  float s1 = 0.f, s2 = 0.f;
#pragma unroll
  for (int k = 0; k < 2; ++k) {
    const int n = 2 * p + k;
    const f32x4* base = reinterpret_cast<const f32x4*>(out_pre + (n * CB + o) * (TB * VB));
    for (int idx = tid; idx < TB * VB / 4; idx += 256) {
      f32x4 v = base[idx];
#pragma unroll
      for (int j = 0; j < 4; ++j) { s1 += v[j]; s2 += v[j] * v[j]; }
    }
  }
#pragma unroll
  for (int off = 1; off < 64; off <<= 1) {
    s1 += __shfl_xor(s1, off, 64);
    s2 += __shfl_xor(s2, off, 64);
  }
  const int wave = tid >> 6;
  if ((tid & 63) == 0) { ws1[wave] = s1; ws2[wave] = s2; }
  __syncthreads();
  if (tid == 0) {
    float r1 = ws1[0] + ws1[1] + ws1[2] + ws1[3];
    float r2 = ws2[0] + ws2[1] + ws2[2] + ws2[3];
    atomicAdd(&stats2[o], r1);
    atomicAdd(&stats2[96 + o], r2);
  }
}

// ---------------- K5: BN2 finalize (float4 elementwise) ----------------
__global__ __launch_bounds__(256) void k5_bn2(
    const float* __restrict__ out_pre, const float* __restrict__ stats2,
    const float* __restrict__ g2, const float* __restrict__ bt2,
    float* __restrict__ out) {
  int idx = blockIdx.x * 256 + threadIdx.x;
  if (idx >= NB * CB * TB * VB / 4) return;
  int o = (idx / (TB * VB / 4)) % CB;
  const float inv = 1.f / (8.f * 128.f * 25.f);
  float m = stats2[o] * inv;
  float var = stats2[96 + o] * inv - m * m;
  float a = g2[o] * rsqrtf(var + EPSB);
  float b = bt2[o] - m * a;
  f32x4 vin = reinterpret_cast<const f32x4*>(out_pre)[idx];
  f32x4 vo;
#pragma unroll
  for (int j = 0; j < 4; ++j) vo[j] = a * vin[j] + b;
  reinterpret_cast<f32x4*>(out)[idx] = vo;
}

extern "C" void kernel_launch(void* const* d_in, const int* in_sizes, int n_in,
                              void* d_out, int out_size, void* d_ws, size_t ws_size,
                              hipStream_t stream) {
  const float* x   = (const float*)d_in[0];
  const float* As  = (const float*)d_in[1];
  const float* Bs  = (const float*)d_in[2];
  const float* Ar  = (const float*)d_in[3];
  const float* Wm  = (const float*)d_in[4];
  const float* bm  = (const float*)d_in[5];
  const float* g1  = (const float*)d_in[6];
  const float* bt1 = (const float*)d_in[7];
  const float* Wo  = (const float*)d_in[8];
  const float* bo  = (const float*)d_in[9];
  const float* g2  = (const float*)d_in[10];
  const float* bt2 = (const float*)d_in[11];
  float* out = (float*)d_out;

  char* base = (char*)d_ws;
  unsigned short* HR   = (unsigned short*)base;                  // 14,745,600 B
  float* out_pre       = (float*)(base + 14745600);              //  9,830,400 B
  unsigned short* ABsw = (unsigned short*)(base + 24576000);     //    184,320 B
  unsigned short* Wsw  = (unsigned short*)(base + 24760320);     //    221,184 B
  unsigned short* Wosw = (unsigned short*)(base + 24981504);     //     55,296 B
  float* stats         = (float*)(base + 25036800);              //      1,536 B
  float* stats1 = stats, *stats2 = stats + 192;

  k0_init<<<432, 256, 0, stream>>>(As, Bs, Ar, Wm, Wo, ABsw, Wsw, Wosw, stats);
  k1t2<<<NB * TB / 2, 384, 0, stream>>>(x, ABsw, Wsw, bm, HR, stats1);
  k3n<<<NB * TB / 2, 384, 0, stream>>>(HR, stats1, g1, bt1, Wosw, bo, out_pre);
  k4_stats<<<CB * 4, 256, 0, stream>>>(out_pre, stats2);
  k5_bn2<<<(NB * CB * TB * VB / 4 + 255) / 256, 256, 0, stream>>>(out_pre, stats2, g2, bt2, out);
}